// Round 1
// baseline (617.065 us; speedup 1.0000x reference)
//
#include <hip/hip_runtime.h>
#include <math.h>

#define D_MODEL 512
#define BATCH 8
#define SEQ 512
#define HEAD 64
#define DK 4
#define DV 8
#define HIDD 10
#define PR 8  // rows per proj block

// ---------------------------------------------------------------------------
// Projection: Q = xq @ WqM, K = xkv @ WkM, V = xkv @ WvM
// One block handles PR=8 consecutive rows; 256 threads; thread t owns output
// columns {t} of Q/K and {t, t+256} of V. Weights are read coalesced from
// global (2 MB, L2-resident); x rows are broadcast from LDS ([c][r] layout so
// the r-unrolled reads are contiguous 32B chunks -> ds_read_b128).
// ---------------------------------------------------------------------------
__global__ __launch_bounds__(256) void proj_kernel(
    const float* __restrict__ xq, const float* __restrict__ xkv,
    const float* __restrict__ Wq, const float* __restrict__ Wk,
    const float* __restrict__ Wv,
    float* __restrict__ Q, float* __restrict__ K, float* __restrict__ V)
{
    __shared__ float lq[D_MODEL][PR];   // [c][r]
    __shared__ float lkv[D_MODEL][PR];
    const int t = threadIdx.x;
    const int r0 = blockIdx.x * PR;

    for (int i = t; i < PR * D_MODEL; i += 256) {
        int r = i >> 9;        // i / 512
        int c = i & 511;       // i % 512
        lq[c][r]  = xq [(long)(r0 + r) * D_MODEL + c];
        lkv[c][r] = xkv[(long)(r0 + r) * D_MODEL + c];
    }
    __syncthreads();

    float aq[PR], ak[PR], av0[PR], av1[PR];
#pragma unroll
    for (int r = 0; r < PR; ++r) { aq[r] = 0.f; ak[r] = 0.f; av0[r] = 0.f; av1[r] = 0.f; }

    for (int c = 0; c < D_MODEL; ++c) {
        float wq  = Wq[c * 256 + t];
        float wk  = Wk[c * 256 + t];
        float wv0 = Wv[c * 512 + t];
        float wv1 = Wv[c * 512 + t + 256];
#pragma unroll
        for (int r = 0; r < PR; ++r) {
            float xv = lq[c][r];
            float kv = lkv[c][r];
            aq[r]  += xv * wq;
            ak[r]  += kv * wk;
            av0[r] += kv * wv0;
            av1[r] += kv * wv1;
        }
    }

#pragma unroll
    for (int r = 0; r < PR; ++r) {
        long row = r0 + r;
        Q[row * 256 + t]       = aq[r];
        K[row * 256 + t]       = ak[r];
        V[row * 512 + t]       = av0[r];
        V[row * 512 + t + 256] = av1[r];
    }
}

// ---------------------------------------------------------------------------
// Attention for one (b, h): K/V slices in LDS, 2 queries per thread,
// two-pass softmax (exact max, like jax). Faithful quirk: multiplicative
// tril mask -> masked scores are exactly 0 and STILL participate in softmax.
// ---------------------------------------------------------------------------
__global__ __launch_bounds__(256) void attn_kernel(
    const float* __restrict__ Q, const float* __restrict__ K,
    const float* __restrict__ V, float* __restrict__ O, int causal)
{
    __shared__ float Kl[SEQ * DK];   // 8 KB
    __shared__ float Vl[SEQ * DV];   // 16 KB
    const int t = threadIdx.x;
    const int b = blockIdx.x >> 6;
    const int h = blockIdx.x & 63;

    const long kbase = (long)b * SEQ * 256 + h * DK;
    const long vbase = (long)b * SEQ * 512 + h * DV;
    for (int i = t; i < SEQ * DK; i += 256) {
        int s = i >> 2, d = i & 3;
        Kl[i] = K[kbase + (long)s * 256 + d];
    }
    for (int i = t; i < SEQ * DV; i += 256) {
        int s = i >> 3, d = i & 7;
        Vl[i] = V[vbase + (long)s * 512 + d];
    }
    __syncthreads();

#pragma unroll
    for (int qi = 0; qi < 2; ++qi) {
        const int q = t + qi * 256;
        const long qbase = (long)b * SEQ * 256 + (long)q * 256 + h * DK;
        // fold 1/sqrt(DK)=0.5 into Q (exact: power-of-two scale)
        const float q0 = Q[qbase + 0] * 0.5f;
        const float q1 = Q[qbase + 1] * 0.5f;
        const float q2 = Q[qbase + 2] * 0.5f;
        const float q3 = Q[qbase + 3] * 0.5f;

        // pass 1: row max over ALL S entries (masked entries are 0, not -inf)
        float m = -INFINITY;
        for (int s = 0; s < SEQ; ++s) {
            float sc = q0 * Kl[s * 4] + q1 * Kl[s * 4 + 1]
                     + q2 * Kl[s * 4 + 2] + q3 * Kl[s * 4 + 3];
            if (causal && s > q) sc = 0.0f;
            m = fmaxf(m, sc);
        }

        // pass 2: exp + weighted V accumulation (masked entries contribute
        // exp(0 - m) * V[s] — faithful to the multiplicative-mask quirk)
        float l = 0.0f;
        float acc[DV];
#pragma unroll
        for (int d = 0; d < DV; ++d) acc[d] = 0.f;
        for (int s = 0; s < SEQ; ++s) {
            float sc = q0 * Kl[s * 4] + q1 * Kl[s * 4 + 1]
                     + q2 * Kl[s * 4 + 2] + q3 * Kl[s * 4 + 3];
            if (causal && s > q) sc = 0.0f;
            float p = __expf(sc - m);
            l += p;
#pragma unroll
            for (int d = 0; d < DV; ++d) acc[d] += p * Vl[s * 8 + d];
        }
        float inv = 1.0f / l;
        const long obase = (long)b * SEQ * 512 + (long)q * 512 + h * DV;
#pragma unroll
        for (int d = 0; d < DV; ++d) O[obase + d] = acc[d] * inv;
    }
}

// ---------------------------------------------------------------------------
// Fused residual + LayerNorm + MLP (512 -> 10 -> 512). One block per row.
// ---------------------------------------------------------------------------
__global__ __launch_bounds__(256) void ln_mlp_kernel(
    const float* __restrict__ x, const float* __restrict__ fx,
    const float* __restrict__ g, const float* __restrict__ beta,
    const float* __restrict__ w1, const float* __restrict__ b1,
    const float* __restrict__ w2, const float* __restrict__ b2,
    float* __restrict__ out)
{
    __shared__ float red[256];
    __shared__ float wred[HIDD][4];
    __shared__ float hsh[HIDD];
    const int t = threadIdx.x;
    const long base = (long)blockIdx.x * D_MODEL;

    float z0 = x[base + t]       + fx[base + t];
    float z1 = x[base + t + 256] + fx[base + t + 256];

    // mean
    red[t] = z0 + z1;
    __syncthreads();
    for (int off = 128; off > 0; off >>= 1) {
        if (t < off) red[t] += red[t + off];
        __syncthreads();
    }
    float mu = red[0] * (1.0f / 512.0f);
    __syncthreads();

    // variance (population, like jnp.mean of squared deviation)
    float d0 = z0 - mu, d1 = z1 - mu;
    red[t] = d0 * d0 + d1 * d1;
    __syncthreads();
    for (int off = 128; off > 0; off >>= 1) {
        if (t < off) red[t] += red[t + off];
        __syncthreads();
    }
    float var = red[0] * (1.0f / 512.0f);
    float rs = rsqrtf(var + 1e-5f);

    float y0 = d0 * rs * g[t]       + beta[t];
    float y1 = d1 * rs * g[t + 256] + beta[t + 256];

    // fc1: h[i] = relu(sum_c y[c] * w1[i,c] + b1[i]); partial per thread
    float part[HIDD];
#pragma unroll
    for (int i = 0; i < HIDD; ++i)
        part[i] = y0 * w1[i * 512 + t] + y1 * w1[i * 512 + t + 256];

    const int lane = t & 63, wid = t >> 6;
#pragma unroll
    for (int i = 0; i < HIDD; ++i) {
        float v = part[i];
        for (int off = 32; off > 0; off >>= 1) v += __shfl_down(v, off);
        if (lane == 0) wred[i][wid] = v;
    }
    __syncthreads();
    if (t < HIDD) {
        float hv = wred[t][0] + wred[t][1] + wred[t][2] + wred[t][3] + b1[t];
        hsh[t] = fmaxf(hv, 0.0f);
    }
    __syncthreads();

    // fc2: out[c] = sum_i h[i] * w2[c,i] + b2[c]
    float o0 = b2[t], o1 = b2[t + 256];
#pragma unroll
    for (int i = 0; i < HIDD; ++i) {
        o0 += hsh[i] * w2[t * 10 + i];
        o1 += hsh[i] * w2[(t + 256) * 10 + i];
    }
    out[base + t]       = o0;
    out[base + t + 256] = o1;
}

extern "C" void kernel_launch(void* const* d_in, const int* in_sizes, int n_in,
                              void* d_out, int out_size, void* d_ws, size_t ws_size,
                              hipStream_t stream) {
    (void)in_sizes; (void)n_in; (void)out_size; (void)ws_size;
    const float* x    = (const float*)d_in[0];
    const float* xenc = (const float*)d_in[1];
    const float* Wq   = (const float*)d_in[2];
    const float* Wk   = (const float*)d_in[3];
    const float* Wv   = (const float*)d_in[4];
    const float* ln_g = (const float*)d_in[5];
    const float* ln_b = (const float*)d_in[6];
    const float* w1   = (const float*)d_in[7];
    const float* b1   = (const float*)d_in[8];
    const float* w2   = (const float*)d_in[9];
    const float* b2   = (const float*)d_in[10];
    float* out = (float*)d_out;

    float* ws = (float*)d_ws;
    float* Q = ws;                    // B*S*HEAD*DK = 1,048,576 floats
    float* K = Q + 1048576;           // 1,048,576 floats
    float* V = K + 1048576;           // B*S*HEAD*DV = 2,097,152 floats
    float* A = V + 2097152;           // attn output, 2,097,152 floats (reused)

    const int nrows = BATCH * SEQ;    // 4096

    // Stage 1: self-attention (causal multiplicative mask)
    proj_kernel<<<dim3(nrows / PR), 256, 0, stream>>>(x, x, Wq, Wk, Wv, Q, K, V);
    attn_kernel<<<dim3(BATCH * HEAD), 256, 0, stream>>>(Q, K, V, A, 1);

    // Stage 2: cross-attention (same weights — faithful quirk)
    proj_kernel<<<dim3(nrows / PR), 256, 0, stream>>>(A, xenc, Wq, Wk, Wv, Q, K, V);
    attn_kernel<<<dim3(BATCH * HEAD), 256, 0, stream>>>(Q, K, V, A, 0);

    // Stage 3: residual(x) + LayerNorm + MLP
    ln_mlp_kernel<<<dim3(nrows), 256, 0, stream>>>(x, A, ln_g, ln_b,
                                                   w1, b1, w2, b2, out);
}

// Round 2
// 567.672 us; speedup vs baseline: 1.0870x; 1.0870x over previous
//
#include <hip/hip_runtime.h>
#include <math.h>

#define D_MODEL 512
#define BATCH 8
#define SEQ 512
#define HEAD 64
#define DK 4
#define DV 8
#define HIDD 10
#define PR 8  // rows per proj block

// ---------------------------------------------------------------------------
// Projection: Q = xq @ WqM, K = xkv @ WkM, V = xkv @ WvM  (unchanged from R0)
// ---------------------------------------------------------------------------
__global__ __launch_bounds__(256) void proj_kernel(
    const float* __restrict__ xq, const float* __restrict__ xkv,
    const float* __restrict__ Wq, const float* __restrict__ Wk,
    const float* __restrict__ Wv,
    float* __restrict__ Q, float* __restrict__ K, float* __restrict__ V)
{
    __shared__ float lq[D_MODEL][PR];   // [c][r]
    __shared__ float lkv[D_MODEL][PR];
    const int t = threadIdx.x;
    const int r0 = blockIdx.x * PR;

    for (int i = t; i < PR * D_MODEL; i += 256) {
        int r = i >> 9;
        int c = i & 511;
        lq[c][r]  = xq [(long)(r0 + r) * D_MODEL + c];
        lkv[c][r] = xkv[(long)(r0 + r) * D_MODEL + c];
    }
    __syncthreads();

    float aq[PR], ak[PR], av0[PR], av1[PR];
#pragma unroll
    for (int r = 0; r < PR; ++r) { aq[r] = 0.f; ak[r] = 0.f; av0[r] = 0.f; av1[r] = 0.f; }

    for (int c = 0; c < D_MODEL; ++c) {
        float wq  = Wq[c * 256 + t];
        float wk  = Wk[c * 256 + t];
        float wv0 = Wv[c * 512 + t];
        float wv1 = Wv[c * 512 + t + 256];
#pragma unroll
        for (int r = 0; r < PR; ++r) {
            float xv = lq[c][r];
            float kv = lkv[c][r];
            aq[r]  += xv * wq;
            ak[r]  += kv * wk;
            av0[r] += kv * wv0;
            av1[r] += kv * wv1;
        }
    }

#pragma unroll
    for (int r = 0; r < PR; ++r) {
        long row = r0 + r;
        Q[row * 256 + t]       = aq[r];
        K[row * 256 + t]       = ak[r];
        V[row * 512 + t]       = av0[r];
        V[row * 512 + t + 256] = av1[r];
    }
}

// ---------------------------------------------------------------------------
// Attention: one block per (b, h, q-half); 256 threads, 1 query/thread.
// Dynamic LDS: Kl[SEQ*DK] | Vl[SEQ*DV] | (causal only) Sv[(SEQ+1)*DV] | cs[33*DV]
// Causal quirk preserved: masked (s>q) scores are exactly 0 and participate in
// softmax. Shortcut: their total contribution is exp(-m)*(count, suffixSumV).
// ---------------------------------------------------------------------------
__global__ __launch_bounds__(256) void attn_kernel(
    const float* __restrict__ Q, const float* __restrict__ K,
    const float* __restrict__ V, float* __restrict__ O, int causal)
{
    extern __shared__ float smem[];
    float* Kl = smem;                    // SEQ*DK   = 2048 floats
    float* Vl = smem + SEQ * DK;         // SEQ*DV   = 4096 floats
    float* Sv = Vl + SEQ * DV;           // (SEQ+1)*DV = 4104 floats (causal)
    float* cs = Sv + (SEQ + 1) * DV;     // 33*DV = 264 floats (causal)

    const int t = threadIdx.x;
    const int bh = blockIdx.x >> 1;
    const int qhalf = blockIdx.x & 1;
    const int b = bh >> 6;
    const int h = bh & 63;

    const long kbase = (long)b * SEQ * 256 + h * DK;
    const long vbase = (long)b * SEQ * 512 + h * DV;
    for (int i = t; i < SEQ * DK; i += 256) {
        int s = i >> 2, d = i & 3;
        Kl[i] = K[kbase + (long)s * 256 + d];
    }
    for (int i = t; i < SEQ * DV; i += 256) {
        int s = i >> 3, d = i & 7;
        Vl[i] = V[vbase + (long)s * 512 + d];
    }
    __syncthreads();

    if (causal) {
        // Suffix sums of V: Sv[s][d] = sum_{s'>=s} Vl[s'][d]; Sv[SEQ][d] = 0.
        const int d = t & 7;
        const int chunk = t >> 3;         // 32 chunks of 16
        float csum = 0.f;
#pragma unroll
        for (int i = 0; i < 16; ++i) csum += Vl[(chunk * 16 + i) * 8 + d];
        cs[chunk * 8 + d] = csum;
        __syncthreads();
        if (t < 8) {                      // t == d; serial suffix over 32 chunks
            cs[32 * 8 + t] = 0.f;
            float run = 0.f;
            for (int c2 = 31; c2 >= 0; --c2) {
                run += cs[c2 * 8 + t];
                cs[c2 * 8 + t] = run;     // inclusive suffix of chunk c2
            }
        }
        __syncthreads();
        float run = cs[(chunk + 1) * 8 + d];
#pragma unroll
        for (int i = 15; i >= 0; --i) {
            int s = chunk * 16 + i;
            run += Vl[s * 8 + d];
            Sv[s * 8 + d] = run;
        }
        if (t < 8) Sv[SEQ * 8 + t] = 0.f;
        __syncthreads();
    }

    const int q = qhalf * 256 + t;
    const long qbase = (long)b * SEQ * 256 + (long)q * 256 + h * DK;
    const float4 qv = *(const float4*)(Q + qbase);
    // fold 1/sqrt(DK)=0.5 into Q (exact pow2 scale)
    const float q0 = qv.x * 0.5f, q1 = qv.y * 0.5f;
    const float q2 = qv.z * 0.5f, q3 = qv.w * 0.5f;

    const int bound = causal ? q : (SEQ - 1);

    // pass 1: max over unmasked scores
    float m = -INFINITY;
#pragma unroll 4
    for (int s = 0; s <= bound; ++s) {
        float4 k4 = *(const float4*)(Kl + s * 4);
        float sc = fmaf(q0, k4.x, fmaf(q1, k4.y, fmaf(q2, k4.z, q3 * k4.w)));
        m = fmaxf(m, sc);
    }
    if (causal && q < SEQ - 1) m = fmaxf(m, 0.f);  // masked zeros participate

    // pass 2: exp + weighted V accumulation over unmasked range
    float l = 0.f;
    float a0 = 0.f, a1 = 0.f, a2 = 0.f, a3 = 0.f;
    float a4 = 0.f, a5 = 0.f, a6 = 0.f, a7 = 0.f;
#pragma unroll 2
    for (int s = 0; s <= bound; ++s) {
        float4 k4 = *(const float4*)(Kl + s * 4);
        float sc = fmaf(q0, k4.x, fmaf(q1, k4.y, fmaf(q2, k4.z, q3 * k4.w)));
        float p = __expf(sc - m);
        l += p;
        float4 v0 = *(const float4*)(Vl + s * 8);
        float4 v1 = *(const float4*)(Vl + s * 8 + 4);
        a0 += p * v0.x; a1 += p * v0.y; a2 += p * v0.z; a3 += p * v0.w;
        a4 += p * v1.x; a5 += p * v1.y; a6 += p * v1.z; a7 += p * v1.w;
    }

    if (causal) {
        // masked entries: each contributes exp(0 - m); count = SEQ-1-q;
        // V-weighted total = exp(-m) * suffixSum(V, q+1).
        float pm = __expf(-m);
        l += pm * (float)(SEQ - 1 - q);
        const float* sv = Sv + (q + 1) * 8;
        a0 += pm * sv[0]; a1 += pm * sv[1]; a2 += pm * sv[2]; a3 += pm * sv[3];
        a4 += pm * sv[4]; a5 += pm * sv[5]; a6 += pm * sv[6]; a7 += pm * sv[7];
    }

    float inv = 1.0f / l;
    const long obase = (long)b * SEQ * 512 + (long)q * 512 + h * DV;
    float4 o0 = make_float4(a0 * inv, a1 * inv, a2 * inv, a3 * inv);
    float4 o1 = make_float4(a4 * inv, a5 * inv, a6 * inv, a7 * inv);
    *(float4*)(O + obase)     = o0;
    *(float4*)(O + obase + 4) = o1;
}

// ---------------------------------------------------------------------------
// Fused residual + LayerNorm + MLP (512 -> 10 -> 512). One block per row.
// ---------------------------------------------------------------------------
__global__ __launch_bounds__(256) void ln_mlp_kernel(
    const float* __restrict__ x, const float* __restrict__ fx,
    const float* __restrict__ g, const float* __restrict__ beta,
    const float* __restrict__ w1, const float* __restrict__ b1,
    const float* __restrict__ w2, const float* __restrict__ b2,
    float* __restrict__ out)
{
    __shared__ float red[256];
    __shared__ float wred[HIDD][4];
    __shared__ float hsh[HIDD];
    const int t = threadIdx.x;
    const long base = (long)blockIdx.x * D_MODEL;

    float z0 = x[base + t]       + fx[base + t];
    float z1 = x[base + t + 256] + fx[base + t + 256];

    red[t] = z0 + z1;
    __syncthreads();
    for (int off = 128; off > 0; off >>= 1) {
        if (t < off) red[t] += red[t + off];
        __syncthreads();
    }
    float mu = red[0] * (1.0f / 512.0f);
    __syncthreads();

    float d0 = z0 - mu, d1 = z1 - mu;
    red[t] = d0 * d0 + d1 * d1;
    __syncthreads();
    for (int off = 128; off > 0; off >>= 1) {
        if (t < off) red[t] += red[t + off];
        __syncthreads();
    }
    float var = red[0] * (1.0f / 512.0f);
    float rs = rsqrtf(var + 1e-5f);

    float y0 = d0 * rs * g[t]       + beta[t];
    float y1 = d1 * rs * g[t + 256] + beta[t + 256];

    float part[HIDD];
#pragma unroll
    for (int i = 0; i < HIDD; ++i)
        part[i] = y0 * w1[i * 512 + t] + y1 * w1[i * 512 + t + 256];

    const int lane = t & 63, wid = t >> 6;
#pragma unroll
    for (int i = 0; i < HIDD; ++i) {
        float v = part[i];
        for (int off = 32; off > 0; off >>= 1) v += __shfl_down(v, off);
        if (lane == 0) wred[i][wid] = v;
    }
    __syncthreads();
    if (t < HIDD) {
        float hv = wred[t][0] + wred[t][1] + wred[t][2] + wred[t][3] + b1[t];
        hsh[t] = fmaxf(hv, 0.0f);
    }
    __syncthreads();

    float o0 = b2[t], o1 = b2[t + 256];
#pragma unroll
    for (int i = 0; i < HIDD; ++i) {
        o0 += hsh[i] * w2[t * 10 + i];
        o1 += hsh[i] * w2[(t + 256) * 10 + i];
    }
    out[base + t]       = o0;
    out[base + t + 256] = o1;
}

extern "C" void kernel_launch(void* const* d_in, const int* in_sizes, int n_in,
                              void* d_out, int out_size, void* d_ws, size_t ws_size,
                              hipStream_t stream) {
    (void)in_sizes; (void)n_in; (void)out_size; (void)ws_size;
    const float* x    = (const float*)d_in[0];
    const float* xenc = (const float*)d_in[1];
    const float* Wq   = (const float*)d_in[2];
    const float* Wk   = (const float*)d_in[3];
    const float* Wv   = (const float*)d_in[4];
    const float* ln_g = (const float*)d_in[5];
    const float* ln_b = (const float*)d_in[6];
    const float* w1   = (const float*)d_in[7];
    const float* b1   = (const float*)d_in[8];
    const float* w2   = (const float*)d_in[9];
    const float* b2   = (const float*)d_in[10];
    float* out = (float*)d_out;

    float* ws = (float*)d_ws;
    float* Q = ws;                    // 1,048,576 floats
    float* K = Q + 1048576;           // 1,048,576 floats
    float* V = K + 1048576;           // 2,097,152 floats
    float* A = V + 2097152;           // 2,097,152 floats

    const int nrows = BATCH * SEQ;    // 4096

    const size_t lds_cross  = (size_t)(SEQ * DK + SEQ * DV) * 4;                       // 24576 B
    const size_t lds_causal = lds_cross + (size_t)((SEQ + 1) * DV + 33 * DV) * 4;      // +17472 B

    // Stage 1: self-attention (causal multiplicative mask)
    proj_kernel<<<dim3(nrows / PR), 256, 0, stream>>>(x, x, Wq, Wk, Wv, Q, K, V);
    attn_kernel<<<dim3(BATCH * HEAD * 2), 256, lds_causal, stream>>>(Q, K, V, A, 1);

    // Stage 2: cross-attention (same weights — faithful quirk)
    proj_kernel<<<dim3(nrows / PR), 256, 0, stream>>>(A, xenc, Wq, Wk, Wv, Q, K, V);
    attn_kernel<<<dim3(BATCH * HEAD * 2), 256, lds_cross, stream>>>(Q, K, V, A, 0);

    // Stage 3: residual(x) + LayerNorm + MLP
    ln_mlp_kernel<<<dim3(nrows), 256, 0, stream>>>(x, A, ln_g, ln_b,
                                                   w1, b1, w2, b2, out);
}

// Round 3
// 448.314 us; speedup vs baseline: 1.3764x; 1.2662x over previous
//
#include <hip/hip_runtime.h>
#include <math.h>

#define D_MODEL 512
#define BATCH 8
#define SEQ 512
#define HEAD 64
#define DK 4
#define DV 8
#define HIDD 10
#define PR 16  // rows per proj block

// ---------------------------------------------------------------------------
// Projection: Q = xq @ WqM, K = xkv @ WkM, V = xkv @ WvM.
// 512 threads: col = tid&255, h2 = tid>>8 selects 8 of the block's 16 rows.
// Both halves read identical weight addresses -> L1 dedup halves L2 traffic.
// Grid 256 blocks (1/CU). SAME=1: xq==xkv, stage one LDS array (32 KB).
// ---------------------------------------------------------------------------
template <bool SAME>
__global__ __launch_bounds__(512) void proj_kernel(
    const float* __restrict__ xq, const float* __restrict__ xkv,
    const float* __restrict__ Wq, const float* __restrict__ Wk,
    const float* __restrict__ Wv,
    float* __restrict__ Q, float* __restrict__ K, float* __restrict__ V)
{
    extern __shared__ float sm[];
    float* lkv = sm;                       // [c][16] = 8192 floats
    float* lq  = SAME ? sm : sm + 8192;    // [c][16] = 8192 floats (if distinct)

    const int tid = threadIdx.x;
    const int col = tid & 255;
    const int h2  = tid >> 8;
    const int r0b = blockIdx.x * PR;

    for (int i = tid; i < PR * D_MODEL; i += 512) {
        int r = i >> 9;
        int c = i & 511;
        lkv[c * PR + r] = xkv[(long)(r0b + r) * D_MODEL + c];
        if (!SAME) lq[c * PR + r] = xq[(long)(r0b + r) * D_MODEL + c];
    }
    __syncthreads();

    float aq[8], ak[8], av0[8], av1[8];
#pragma unroll
    for (int r = 0; r < 8; ++r) { aq[r] = 0.f; ak[r] = 0.f; av0[r] = 0.f; av1[r] = 0.f; }

#pragma unroll 2
    for (int c = 0; c < D_MODEL; ++c) {
        float wq  = Wq[c * 256 + col];
        float wk  = Wk[c * 256 + col];
        float wv0 = Wv[c * 512 + col];
        float wv1 = Wv[c * 512 + col + 256];
        const float4 k0 = *(const float4*)(lkv + c * PR + h2 * 8);
        const float4 k1 = *(const float4*)(lkv + c * PR + h2 * 8 + 4);
        float xk[8] = {k0.x, k0.y, k0.z, k0.w, k1.x, k1.y, k1.z, k1.w};
        float xq8[8];
        if (SAME) {
#pragma unroll
            for (int r = 0; r < 8; ++r) xq8[r] = xk[r];
        } else {
            const float4 a0 = *(const float4*)(lq + c * PR + h2 * 8);
            const float4 a1 = *(const float4*)(lq + c * PR + h2 * 8 + 4);
            xq8[0]=a0.x; xq8[1]=a0.y; xq8[2]=a0.z; xq8[3]=a0.w;
            xq8[4]=a1.x; xq8[5]=a1.y; xq8[6]=a1.z; xq8[7]=a1.w;
        }
#pragma unroll
        for (int r = 0; r < 8; ++r) {
            aq[r]  = fmaf(xq8[r], wq,  aq[r]);
            ak[r]  = fmaf(xk[r],  wk,  ak[r]);
            av0[r] = fmaf(xk[r],  wv0, av0[r]);
            av1[r] = fmaf(xk[r],  wv1, av1[r]);
        }
    }

#pragma unroll
    for (int r = 0; r < 8; ++r) {
        long row = r0b + h2 * 8 + r;
        Q[row * 256 + col]       = aq[r];
        K[row * 256 + col]       = ak[r];
        V[row * 512 + col]       = av0[r];
        V[row * 512 + col + 256] = av1[r];
    }
}

// ---------------------------------------------------------------------------
// Attention: one block per (b, h, q-half); 256 threads, 1 query/thread.
// Online softmax (single pass), 8 s-values per group for MLP/ILP.
// Causal quirk preserved: masked (s>q) scores are exactly 0 and participate;
// their lump = exp(-M) * (count, suffixSumV) via chunk-granular suffix sums.
// ---------------------------------------------------------------------------
__global__ __launch_bounds__(256) void attn_kernel(
    const float* __restrict__ Q, const float* __restrict__ K,
    const float* __restrict__ V, float* __restrict__ O, int causal)
{
    extern __shared__ float smem[];
    float* Kl = smem;                 // SEQ*DK = 2048 floats
    float* Vl = smem + SEQ * DK;      // SEQ*DV = 4096 floats
    float* cs = Vl + SEQ * DV;        // 33*DV  =  264 floats (causal only)

    const int t = threadIdx.x;
    const int bh = blockIdx.x >> 1;
    const int qhalf = blockIdx.x & 1;
    const int b = bh >> 6;
    const int h = bh & 63;

    const long kbase = (long)b * SEQ * 256 + h * DK;
    const long vbase = (long)b * SEQ * 512 + h * DV;
    for (int i = t; i < SEQ * DK; i += 256) {
        int s = i >> 2, d = i & 3;
        Kl[i] = K[kbase + (long)s * 256 + d];
    }
    for (int i = t; i < SEQ * DV; i += 256) {
        int s = i >> 3, d = i & 7;
        Vl[i] = V[vbase + (long)s * 512 + d];
    }
    __syncthreads();

    if (causal) {
        // chunk sums: cs[ch][d] = sum of V over chunk ch (16 s-values)
        const int ch = t >> 3, d = t & 7;
        float s16 = 0.f;
#pragma unroll
        for (int i = 0; i < 16; ++i) s16 += Vl[(ch * 16 + i) * 8 + d];
        cs[ch * 8 + d] = s16;
        __syncthreads();
        if (t < 8) {  // in-place inclusive suffix over 32 chunks; sentinel ch=32
            cs[256 + t] = 0.f;
            float run = 0.f;
            for (int c2 = 31; c2 >= 0; --c2) {
                run += cs[c2 * 8 + t];
                cs[c2 * 8 + t] = run;
            }
        }
        __syncthreads();
    }

    const int q = qhalf * 256 + t;
    const long qbase = (long)b * SEQ * 256 + (long)q * 256 + h * DK;
    const float4 qv = *(const float4*)(Q + qbase);
    const float q0 = qv.x * 0.5f, q1 = qv.y * 0.5f;   // fold 1/sqrt(DK)=0.5
    const float q2 = qv.z * 0.5f, q3 = qv.w * 0.5f;

    const int bound = causal ? q : (SEQ - 1);

    float m = -INFINITY, l = 0.f;
    float a0=0.f,a1=0.f,a2=0.f,a3=0.f,a4=0.f,a5=0.f,a6=0.f,a7=0.f;

    int s0 = 0;
    for (; s0 + 8 <= bound + 1; s0 += 8) {
        float sc[8];
#pragma unroll
        for (int i = 0; i < 8; ++i) {
            const float4 k4 = *(const float4*)(Kl + (s0 + i) * 4);
            sc[i] = fmaf(q0, k4.x, fmaf(q1, k4.y, fmaf(q2, k4.z, q3 * k4.w)));
        }
        float gm = fmaxf(fmaxf(fmaxf(sc[0], sc[1]), fmaxf(sc[2], sc[3])),
                         fmaxf(fmaxf(sc[4], sc[5]), fmaxf(sc[6], sc[7])));
        if (gm > m) {
            float scale = __expf(m - gm);
            l *= scale;
            a0*=scale; a1*=scale; a2*=scale; a3*=scale;
            a4*=scale; a5*=scale; a6*=scale; a7*=scale;
            m = gm;
        }
#pragma unroll
        for (int i = 0; i < 8; ++i) {
            float p = __expf(sc[i] - m);
            l += p;
            const float4 v0 = *(const float4*)(Vl + (s0 + i) * 8);
            const float4 v1 = *(const float4*)(Vl + (s0 + i) * 8 + 4);
            a0 = fmaf(p, v0.x, a0); a1 = fmaf(p, v0.y, a1);
            a2 = fmaf(p, v0.z, a2); a3 = fmaf(p, v0.w, a3);
            a4 = fmaf(p, v1.x, a4); a5 = fmaf(p, v1.y, a5);
            a6 = fmaf(p, v1.z, a6); a7 = fmaf(p, v1.w, a7);
        }
    }
    for (int s = s0; s <= bound; ++s) {  // divergent tail (<8 per lane)
        const float4 k4 = *(const float4*)(Kl + s * 4);
        float sc = fmaf(q0, k4.x, fmaf(q1, k4.y, fmaf(q2, k4.z, q3 * k4.w)));
        if (sc > m) {
            float scale = __expf(m - sc);
            l *= scale;
            a0*=scale; a1*=scale; a2*=scale; a3*=scale;
            a4*=scale; a5*=scale; a6*=scale; a7*=scale;
            m = sc;
        }
        float p = __expf(sc - m);
        l += p;
        const float4 v0 = *(const float4*)(Vl + s * 8);
        const float4 v1 = *(const float4*)(Vl + s * 8 + 4);
        a0 = fmaf(p, v0.x, a0); a1 = fmaf(p, v0.y, a1);
        a2 = fmaf(p, v0.z, a2); a3 = fmaf(p, v0.w, a3);
        a4 = fmaf(p, v1.x, a4); a5 = fmaf(p, v1.y, a5);
        a6 = fmaf(p, v1.z, a6); a7 = fmaf(p, v1.w, a7);
    }

    if (causal && q < SEQ - 1) {
        // masked zeros participate: lump = exp(0 - M) * (count, suffixSumV)
        float M = fmaxf(m, 0.f);
        float scale = __expf(m - M);
        float pm = __expf(-M);
        l = l * scale + pm * (float)(SEQ - 1 - q);
        int nq = q + 1;
        int cq = nq >> 4;
        float sv[8];
#pragma unroll
        for (int d = 0; d < 8; ++d) sv[d] = cs[(cq + 1) * 8 + d];
        for (int s = nq; s < (cq + 1) * 16; ++s) {
            const float4 v0 = *(const float4*)(Vl + s * 8);
            const float4 v1 = *(const float4*)(Vl + s * 8 + 4);
            sv[0]+=v0.x; sv[1]+=v0.y; sv[2]+=v0.z; sv[3]+=v0.w;
            sv[4]+=v1.x; sv[5]+=v1.y; sv[6]+=v1.z; sv[7]+=v1.w;
        }
        a0 = a0*scale + pm*sv[0]; a1 = a1*scale + pm*sv[1];
        a2 = a2*scale + pm*sv[2]; a3 = a3*scale + pm*sv[3];
        a4 = a4*scale + pm*sv[4]; a5 = a5*scale + pm*sv[5];
        a6 = a6*scale + pm*sv[6]; a7 = a7*scale + pm*sv[7];
    }

    float inv = 1.0f / l;
    const long obase = (long)b * SEQ * 512 + (long)q * 512 + h * DV;
    *(float4*)(O + obase)     = make_float4(a0*inv, a1*inv, a2*inv, a3*inv);
    *(float4*)(O + obase + 4) = make_float4(a4*inv, a5*inv, a6*inv, a7*inv);
}

// ---------------------------------------------------------------------------
// Fused residual + LayerNorm + MLP (512 -> 10 -> 512).
// One WAVE per row (no __syncthreads); 256 threads = 4 rows/block.
// ---------------------------------------------------------------------------
__global__ __launch_bounds__(256) void ln_mlp_kernel(
    const float* __restrict__ x, const float* __restrict__ fx,
    const float* __restrict__ g, const float* __restrict__ beta,
    const float* __restrict__ w1, const float* __restrict__ b1,
    const float* __restrict__ w2, const float* __restrict__ b2,
    float* __restrict__ out)
{
    const int t = threadIdx.x;
    const int lane = t & 63;
    const int row = blockIdx.x * 4 + (t >> 6);
    const long base = (long)row * D_MODEL;
    const int e0 = lane * 8;

    const float4 xa = *(const float4*)(x + base + e0);
    const float4 xb = *(const float4*)(x + base + e0 + 4);
    const float4 fa = *(const float4*)(fx + base + e0);
    const float4 fb = *(const float4*)(fx + base + e0 + 4);
    float z[8] = {xa.x+fa.x, xa.y+fa.y, xa.z+fa.z, xa.w+fa.w,
                  xb.x+fb.x, xb.y+fb.y, xb.z+fb.z, xb.w+fb.w};

    float sum = 0.f;
#pragma unroll
    for (int j = 0; j < 8; ++j) sum += z[j];
#pragma unroll
    for (int o = 32; o > 0; o >>= 1) sum += __shfl_xor(sum, o);
    float mu = sum * (1.0f / 512.0f);

    float d[8], ss = 0.f;
#pragma unroll
    for (int j = 0; j < 8; ++j) { d[j] = z[j] - mu; ss += d[j] * d[j]; }
#pragma unroll
    for (int o = 32; o > 0; o >>= 1) ss += __shfl_xor(ss, o);
    float rs = rsqrtf(ss * (1.0f / 512.0f) + 1e-5f);

    const float4 ga = *(const float4*)(g + e0);
    const float4 gb = *(const float4*)(g + e0 + 4);
    const float4 ba = *(const float4*)(beta + e0);
    const float4 bb = *(const float4*)(beta + e0 + 4);
    const float gg[8] = {ga.x,ga.y,ga.z,ga.w,gb.x,gb.y,gb.z,gb.w};
    const float bt[8] = {ba.x,ba.y,ba.z,ba.w,bb.x,bb.y,bb.z,bb.w};
    float y[8];
#pragma unroll
    for (int j = 0; j < 8; ++j) y[j] = d[j] * rs * gg[j] + bt[j];

    float part[HIDD];
#pragma unroll
    for (int i = 0; i < HIDD; ++i) {
        const float4 wa = *(const float4*)(w1 + i * 512 + e0);
        const float4 wb = *(const float4*)(w1 + i * 512 + e0 + 4);
        part[i] = y[0]*wa.x + y[1]*wa.y + y[2]*wa.z + y[3]*wa.w
                + y[4]*wb.x + y[5]*wb.y + y[6]*wb.z + y[7]*wb.w;
    }
#pragma unroll
    for (int i = 0; i < HIDD; ++i)
#pragma unroll
        for (int o = 32; o > 0; o >>= 1) part[i] += __shfl_xor(part[i], o);

    float hv[HIDD];
#pragma unroll
    for (int i = 0; i < HIDD; ++i) hv[i] = fmaxf(part[i] + b1[i], 0.f);

    float o8[8];
#pragma unroll
    for (int j = 0; j < 8; ++j) o8[j] = b2[e0 + j];
#pragma unroll
    for (int i = 0; i < HIDD; ++i)
#pragma unroll
        for (int j = 0; j < 8; ++j)
            o8[j] = fmaf(hv[i], w2[(long)(e0 + j) * 10 + i], o8[j]);

    *(float4*)(out + base + e0)     = make_float4(o8[0], o8[1], o8[2], o8[3]);
    *(float4*)(out + base + e0 + 4) = make_float4(o8[4], o8[5], o8[6], o8[7]);
}

extern "C" void kernel_launch(void* const* d_in, const int* in_sizes, int n_in,
                              void* d_out, int out_size, void* d_ws, size_t ws_size,
                              hipStream_t stream) {
    (void)in_sizes; (void)n_in; (void)out_size; (void)ws_size;
    const float* x    = (const float*)d_in[0];
    const float* xenc = (const float*)d_in[1];
    const float* Wq   = (const float*)d_in[2];
    const float* Wk   = (const float*)d_in[3];
    const float* Wv   = (const float*)d_in[4];
    const float* ln_g = (const float*)d_in[5];
    const float* ln_b = (const float*)d_in[6];
    const float* w1   = (const float*)d_in[7];
    const float* b1   = (const float*)d_in[8];
    const float* w2   = (const float*)d_in[9];
    const float* b2   = (const float*)d_in[10];
    float* out = (float*)d_out;

    float* ws = (float*)d_ws;
    float* Q = ws;                    // 1,048,576 floats
    float* K = Q + 1048576;           // 1,048,576 floats
    float* V = K + 1048576;           // 2,097,152 floats
    float* A = V + 2097152;           // 2,097,152 floats

    const int nrows = BATCH * SEQ;    // 4096
    const size_t lds_proj_same = (size_t)(PR * D_MODEL) * 4;        // 32 KB
    const size_t lds_proj_diff = (size_t)(2 * PR * D_MODEL) * 4;    // 64 KB
    const size_t lds_cross  = (size_t)(SEQ * DK + SEQ * DV) * 4;          // 24576
    const size_t lds_causal = lds_cross + (size_t)(33 * DV) * 4;          // 25632

    // Stage 1: self-attention (causal multiplicative mask)
    proj_kernel<true><<<dim3(nrows / PR), 512, lds_proj_same, stream>>>(
        x, x, Wq, Wk, Wv, Q, K, V);
    attn_kernel<<<dim3(BATCH * HEAD * 2), 256, lds_causal, stream>>>(Q, K, V, A, 1);

    // Stage 2: cross-attention (same weights — faithful quirk)
    proj_kernel<false><<<dim3(nrows / PR), 512, lds_proj_diff, stream>>>(
        A, xenc, Wq, Wk, Wv, Q, K, V);
    attn_kernel<<<dim3(BATCH * HEAD * 2), 256, lds_cross, stream>>>(Q, K, V, A, 0);

    // Stage 3: residual(x) + LayerNorm + MLP
    ln_mlp_kernel<<<dim3(nrows / 4), 256, 0, stream>>>(x, A, ln_g, ln_b,
                                                       w1, b1, w2, b2, out);
}

// Round 4
// 355.985 us; speedup vs baseline: 1.7334x; 1.2594x over previous
//
#include <hip/hip_runtime.h>
#include <math.h>

#define D_MODEL 512
#define BATCH 8
#define SEQ 512
#define HEAD 64
#define DK 4
#define DV 8
#define HIDD 10

// proj tiled-GEMM params
#define MR 32    // rows per block
#define KC 64    // k-chunk
#define NC 256   // cols per block

// ---------------------------------------------------------------------------
// Projection as tiled GEMM: [4096 x 512] @ [512 x 1024] -> {Q|K|V}.
// blockIdx = br*4 + bj; bj selects {Wq, Wk, Wv[:,0:256], Wv[:,256:512]}.
// ldw == ldo for every bj. 256 threads; thread = (wave rg: 8 rows) x
// (cq: 4 cols); 8x4 register block; W-frag contiguous b128 (conflict-free),
// x-frag wave-broadcast. LDS 72 KB -> 2 blocks/CU.
// ---------------------------------------------------------------------------
__global__ __launch_bounds__(256) void proj_kernel(
    const float* __restrict__ xq, const float* __restrict__ xkv,
    const float* __restrict__ Wq, const float* __restrict__ Wk,
    const float* __restrict__ Wv,
    float* __restrict__ Q, float* __restrict__ K, float* __restrict__ V)
{
    __shared__ float xt[KC * MR];   // [k][r]  8 KB
    __shared__ float wt[KC * NC];   // [k][c] 64 KB

    const int t  = threadIdx.x;
    const int bj = blockIdx.x & 3;
    const int br = blockIdx.x >> 2;
    const int r0 = br * MR;

    const float* X; const float* W; float* O; int ldw; int c0;
    if (bj == 0)      { X = xq;  W = Wq; O = Q; ldw = 256; c0 = 0;   }
    else if (bj == 1) { X = xkv; W = Wk; O = K; ldw = 256; c0 = 0;   }
    else if (bj == 2) { X = xkv; W = Wv; O = V; ldw = 512; c0 = 0;   }
    else              { X = xkv; W = Wv; O = V; ldw = 512; c0 = 256; }

    const int rg = t >> 6;          // wave id -> rows rg*8..rg*8+7
    const int cq = t & 63;          // cols cq*4..cq*4+3

    float4 acc[8];
#pragma unroll
    for (int r = 0; r < 8; ++r) acc[r] = make_float4(0.f, 0.f, 0.f, 0.f);

    const int rs = t & 31;          // x-staging: row
    const int kq = t >> 5;          // x-staging: k-octet 0..7

    for (int kc = 0; kc < D_MODEL; kc += KC) {
        // ---- stage x tile (transposed [k][r]; 2-way bank groups = free) ----
        const float4 xa = *(const float4*)(X + (long)(r0 + rs) * D_MODEL + kc + kq * 8);
        const float4 xb = *(const float4*)(X + (long)(r0 + rs) * D_MODEL + kc + kq * 8 + 4);
        xt[(kq * 8 + 0) * MR + rs] = xa.x;
        xt[(kq * 8 + 1) * MR + rs] = xa.y;
        xt[(kq * 8 + 2) * MR + rs] = xa.z;
        xt[(kq * 8 + 3) * MR + rs] = xa.w;
        xt[(kq * 8 + 4) * MR + rs] = xb.x;
        xt[(kq * 8 + 5) * MR + rs] = xb.y;
        xt[(kq * 8 + 6) * MR + rs] = xb.z;
        xt[(kq * 8 + 7) * MR + rs] = xb.w;

        // ---- stage W tile: wave rg loads rows i*4+rg, 1 KB contiguous ----
#pragma unroll
        for (int i = 0; i < 16; ++i) {
            const int row = i * 4 + rg;
            const float4 wv = *(const float4*)(W + (long)(kc + row) * ldw + c0 + cq * 4);
            *(float4*)(wt + row * NC + cq * 4) = wv;
        }
        __syncthreads();

        // ---- compute: 8x4 register block, 32 FMA per k ----
#pragma unroll 4
        for (int k = 0; k < KC; ++k) {
            const float4 w4 = *(const float4*)(wt + k * NC + cq * 4);
            const float4 x0 = *(const float4*)(xt + k * MR + rg * 8);
            const float4 x1 = *(const float4*)(xt + k * MR + rg * 8 + 4);
            const float xr[8] = {x0.x, x0.y, x0.z, x0.w, x1.x, x1.y, x1.z, x1.w};
#pragma unroll
            for (int r = 0; r < 8; ++r) {
                acc[r].x = fmaf(xr[r], w4.x, acc[r].x);
                acc[r].y = fmaf(xr[r], w4.y, acc[r].y);
                acc[r].z = fmaf(xr[r], w4.z, acc[r].z);
                acc[r].w = fmaf(xr[r], w4.w, acc[r].w);
            }
        }
        __syncthreads();
    }

#pragma unroll
    for (int r = 0; r < 8; ++r) {
        const long row = r0 + rg * 8 + r;
        *(float4*)(O + row * ldw + c0 + cq * 4) = acc[r];
    }
}

// ---------------------------------------------------------------------------
// Attention: one block per (b, h, q-half); 256 threads, 1 query/thread.
// Online softmax (single pass), 8 s-values per group for ILP.
// Causal quirk preserved: masked (s>q) scores are exactly 0 and participate;
// their lump = exp(-M) * (count, suffixSumV) via chunk-granular suffix sums.
// ---------------------------------------------------------------------------
__global__ __launch_bounds__(256) void attn_kernel(
    const float* __restrict__ Q, const float* __restrict__ K,
    const float* __restrict__ V, float* __restrict__ O, int causal)
{
    extern __shared__ float smem[];
    float* Kl = smem;                 // SEQ*DK = 2048 floats
    float* Vl = smem + SEQ * DK;      // SEQ*DV = 4096 floats
    float* cs = Vl + SEQ * DV;        // 33*DV  =  264 floats (causal only)

    const int t = threadIdx.x;
    const int bh = blockIdx.x >> 1;
    const int qhalf = blockIdx.x & 1;
    const int b = bh >> 6;
    const int h = bh & 63;

    const long kbase = (long)b * SEQ * 256 + h * DK;
    const long vbase = (long)b * SEQ * 512 + h * DV;
    for (int i = t; i < SEQ * DK; i += 256) {
        int s = i >> 2, d = i & 3;
        Kl[i] = K[kbase + (long)s * 256 + d];
    }
    for (int i = t; i < SEQ * DV; i += 256) {
        int s = i >> 3, d = i & 7;
        Vl[i] = V[vbase + (long)s * 512 + d];
    }
    __syncthreads();

    if (causal) {
        const int ch = t >> 3, d = t & 7;
        float s16 = 0.f;
#pragma unroll
        for (int i = 0; i < 16; ++i) s16 += Vl[(ch * 16 + i) * 8 + d];
        cs[ch * 8 + d] = s16;
        __syncthreads();
        if (t < 8) {
            cs[256 + t] = 0.f;
            float run = 0.f;
            for (int c2 = 31; c2 >= 0; --c2) {
                run += cs[c2 * 8 + t];
                cs[c2 * 8 + t] = run;
            }
        }
        __syncthreads();
    }

    const int q = qhalf * 256 + t;
    const long qbase = (long)b * SEQ * 256 + (long)q * 256 + h * DK;
    const float4 qv = *(const float4*)(Q + qbase);
    const float q0 = qv.x * 0.5f, q1 = qv.y * 0.5f;   // fold 1/sqrt(DK)=0.5
    const float q2 = qv.z * 0.5f, q3 = qv.w * 0.5f;

    const int bound = causal ? q : (SEQ - 1);

    float m = -INFINITY, l = 0.f;
    float a0=0.f,a1=0.f,a2=0.f,a3=0.f,a4=0.f,a5=0.f,a6=0.f,a7=0.f;

    int s0 = 0;
    for (; s0 + 8 <= bound + 1; s0 += 8) {
        float sc[8];
#pragma unroll
        for (int i = 0; i < 8; ++i) {
            const float4 k4 = *(const float4*)(Kl + (s0 + i) * 4);
            sc[i] = fmaf(q0, k4.x, fmaf(q1, k4.y, fmaf(q2, k4.z, q3 * k4.w)));
        }
        float gm = fmaxf(fmaxf(fmaxf(sc[0], sc[1]), fmaxf(sc[2], sc[3])),
                         fmaxf(fmaxf(sc[4], sc[5]), fmaxf(sc[6], sc[7])));
        if (gm > m) {
            float scale = __expf(m - gm);
            l *= scale;
            a0*=scale; a1*=scale; a2*=scale; a3*=scale;
            a4*=scale; a5*=scale; a6*=scale; a7*=scale;
            m = gm;
        }
#pragma unroll
        for (int i = 0; i < 8; ++i) {
            float p = __expf(sc[i] - m);
            l += p;
            const float4 v0 = *(const float4*)(Vl + (s0 + i) * 8);
            const float4 v1 = *(const float4*)(Vl + (s0 + i) * 8 + 4);
            a0 = fmaf(p, v0.x, a0); a1 = fmaf(p, v0.y, a1);
            a2 = fmaf(p, v0.z, a2); a3 = fmaf(p, v0.w, a3);
            a4 = fmaf(p, v1.x, a4); a5 = fmaf(p, v1.y, a5);
            a6 = fmaf(p, v1.z, a6); a7 = fmaf(p, v1.w, a7);
        }
    }
    for (int s = s0; s <= bound; ++s) {
        const float4 k4 = *(const float4*)(Kl + s * 4);
        float sc = fmaf(q0, k4.x, fmaf(q1, k4.y, fmaf(q2, k4.z, q3 * k4.w)));
        if (sc > m) {
            float scale = __expf(m - sc);
            l *= scale;
            a0*=scale; a1*=scale; a2*=scale; a3*=scale;
            a4*=scale; a5*=scale; a6*=scale; a7*=scale;
            m = sc;
        }
        float p = __expf(sc - m);
        l += p;
        const float4 v0 = *(const float4*)(Vl + s * 8);
        const float4 v1 = *(const float4*)(Vl + s * 8 + 4);
        a0 = fmaf(p, v0.x, a0); a1 = fmaf(p, v0.y, a1);
        a2 = fmaf(p, v0.z, a2); a3 = fmaf(p, v0.w, a3);
        a4 = fmaf(p, v1.x, a4); a5 = fmaf(p, v1.y, a5);
        a6 = fmaf(p, v1.z, a6); a7 = fmaf(p, v1.w, a7);
    }

    if (causal && q < SEQ - 1) {
        float M = fmaxf(m, 0.f);
        float scale = __expf(m - M);
        float pm = __expf(-M);
        l = l * scale + pm * (float)(SEQ - 1 - q);
        int nq = q + 1;
        int cq2 = nq >> 4;
        float sv[8];
#pragma unroll
        for (int d = 0; d < 8; ++d) sv[d] = cs[(cq2 + 1) * 8 + d];
        for (int s = nq; s < (cq2 + 1) * 16; ++s) {
            const float4 v0 = *(const float4*)(Vl + s * 8);
            const float4 v1 = *(const float4*)(Vl + s * 8 + 4);
            sv[0]+=v0.x; sv[1]+=v0.y; sv[2]+=v0.z; sv[3]+=v0.w;
            sv[4]+=v1.x; sv[5]+=v1.y; sv[6]+=v1.z; sv[7]+=v1.w;
        }
        a0 = a0*scale + pm*sv[0]; a1 = a1*scale + pm*sv[1];
        a2 = a2*scale + pm*sv[2]; a3 = a3*scale + pm*sv[3];
        a4 = a4*scale + pm*sv[4]; a5 = a5*scale + pm*sv[5];
        a6 = a6*scale + pm*sv[6]; a7 = a7*scale + pm*sv[7];
    }

    float inv = 1.0f / l;
    const long obase = (long)b * SEQ * 512 + (long)q * 512 + h * DV;
    *(float4*)(O + obase)     = make_float4(a0*inv, a1*inv, a2*inv, a3*inv);
    *(float4*)(O + obase + 4) = make_float4(a4*inv, a5*inv, a6*inv, a7*inv);
}

// ---------------------------------------------------------------------------
// Fused residual + LayerNorm + MLP (512 -> 10 -> 512).
// One WAVE per row (no __syncthreads); 256 threads = 4 rows/block.
// ---------------------------------------------------------------------------
__global__ __launch_bounds__(256) void ln_mlp_kernel(
    const float* __restrict__ x, const float* __restrict__ fx,
    const float* __restrict__ g, const float* __restrict__ beta,
    const float* __restrict__ w1, const float* __restrict__ b1,
    const float* __restrict__ w2, const float* __restrict__ b2,
    float* __restrict__ out)
{
    const int t = threadIdx.x;
    const int lane = t & 63;
    const int row = blockIdx.x * 4 + (t >> 6);
    const long base = (long)row * D_MODEL;
    const int e0 = lane * 8;

    const float4 xa = *(const float4*)(x + base + e0);
    const float4 xb = *(const float4*)(x + base + e0 + 4);
    const float4 fa = *(const float4*)(fx + base + e0);
    const float4 fb = *(const float4*)(fx + base + e0 + 4);
    float z[8] = {xa.x+fa.x, xa.y+fa.y, xa.z+fa.z, xa.w+fa.w,
                  xb.x+fb.x, xb.y+fb.y, xb.z+fb.z, xb.w+fb.w};

    float sum = 0.f;
#pragma unroll
    for (int j = 0; j < 8; ++j) sum += z[j];
#pragma unroll
    for (int o = 32; o > 0; o >>= 1) sum += __shfl_xor(sum, o);
    float mu = sum * (1.0f / 512.0f);

    float d[8], ss = 0.f;
#pragma unroll
    for (int j = 0; j < 8; ++j) { d[j] = z[j] - mu; ss += d[j] * d[j]; }
#pragma unroll
    for (int o = 32; o > 0; o >>= 1) ss += __shfl_xor(ss, o);
    float rs = rsqrtf(ss * (1.0f / 512.0f) + 1e-5f);

    const float4 ga = *(const float4*)(g + e0);
    const float4 gb = *(const float4*)(g + e0 + 4);
    const float4 ba = *(const float4*)(beta + e0);
    const float4 bb = *(const float4*)(beta + e0 + 4);
    const float gg[8] = {ga.x,ga.y,ga.z,ga.w,gb.x,gb.y,gb.z,gb.w};
    const float bt[8] = {ba.x,ba.y,ba.z,ba.w,bb.x,bb.y,bb.z,bb.w};
    float y[8];
#pragma unroll
    for (int j = 0; j < 8; ++j) y[j] = d[j] * rs * gg[j] + bt[j];

    float part[HIDD];
#pragma unroll
    for (int i = 0; i < HIDD; ++i) {
        const float4 wa = *(const float4*)(w1 + i * 512 + e0);
        const float4 wb = *(const float4*)(w1 + i * 512 + e0 + 4);
        part[i] = y[0]*wa.x + y[1]*wa.y + y[2]*wa.z + y[3]*wa.w
                + y[4]*wb.x + y[5]*wb.y + y[6]*wb.z + y[7]*wb.w;
    }
#pragma unroll
    for (int i = 0; i < HIDD; ++i)
#pragma unroll
        for (int o = 32; o > 0; o >>= 1) part[i] += __shfl_xor(part[i], o);

    float hv[HIDD];
#pragma unroll
    for (int i = 0; i < HIDD; ++i) hv[i] = fmaxf(part[i] + b1[i], 0.f);

    float o8[8];
#pragma unroll
    for (int j = 0; j < 8; ++j) o8[j] = b2[e0 + j];
#pragma unroll
    for (int i = 0; i < HIDD; ++i)
#pragma unroll
        for (int j = 0; j < 8; ++j)
            o8[j] = fmaf(hv[i], w2[(long)(e0 + j) * 10 + i], o8[j]);

    *(float4*)(out + base + e0)     = make_float4(o8[0], o8[1], o8[2], o8[3]);
    *(float4*)(out + base + e0 + 4) = make_float4(o8[4], o8[5], o8[6], o8[7]);
}

extern "C" void kernel_launch(void* const* d_in, const int* in_sizes, int n_in,
                              void* d_out, int out_size, void* d_ws, size_t ws_size,
                              hipStream_t stream) {
    (void)in_sizes; (void)n_in; (void)out_size; (void)ws_size;
    const float* x    = (const float*)d_in[0];
    const float* xenc = (const float*)d_in[1];
    const float* Wq   = (const float*)d_in[2];
    const float* Wk   = (const float*)d_in[3];
    const float* Wv   = (const float*)d_in[4];
    const float* ln_g = (const float*)d_in[5];
    const float* ln_b = (const float*)d_in[6];
    const float* w1   = (const float*)d_in[7];
    const float* b1   = (const float*)d_in[8];
    const float* w2   = (const float*)d_in[9];
    const float* b2   = (const float*)d_in[10];
    float* out = (float*)d_out;

    float* ws = (float*)d_ws;
    float* Q = ws;                    // 1,048,576 floats
    float* K = Q + 1048576;           // 1,048,576 floats
    float* V = K + 1048576;           // 2,097,152 floats
    float* A = V + 2097152;           // 2,097,152 floats

    const int nrows = BATCH * SEQ;    // 4096
    const size_t lds_cross  = (size_t)(SEQ * DK + SEQ * DV) * 4;          // 24576
    const size_t lds_causal = lds_cross + (size_t)(33 * DV) * 4;          // 25632
    const int proj_grid = (nrows / MR) * 4;                               // 512

    // Stage 1: self-attention (causal multiplicative mask)
    proj_kernel<<<dim3(proj_grid), 256, 0, stream>>>(x, x, Wq, Wk, Wv, Q, K, V);
    attn_kernel<<<dim3(BATCH * HEAD * 2), 256, lds_causal, stream>>>(Q, K, V, A, 1);

    // Stage 2: cross-attention (same weights — faithful quirk)
    proj_kernel<<<dim3(proj_grid), 256, 0, stream>>>(A, xenc, Wq, Wk, Wv, Q, K, V);
    attn_kernel<<<dim3(BATCH * HEAD * 2), 256, lds_cross, stream>>>(Q, K, V, A, 0);

    // Stage 3: residual(x) + LayerNorm + MLP
    ln_mlp_kernel<<<dim3(nrows / 4), 256, 0, stream>>>(x, A, ln_g, ln_b,
                                                       w1, b1, w2, b2, out);
}

// Round 5
// 340.781 us; speedup vs baseline: 1.8107x; 1.0446x over previous
//
#include <hip/hip_runtime.h>
#include <math.h>

#define D_MODEL 512
#define BATCH 8
#define SEQ 512
#define HEAD 64
#define DK 4
#define DV 8
#define HIDD 10

// proj tiled-GEMM params
#define MR 32    // rows per block
#define KC 32    // k-chunk (36 KB LDS -> 4 blocks/CU)
#define NC 256   // cols per block

// ---------------------------------------------------------------------------
// Projection as tiled GEMM: [4096 x 512] @ [512 x 1024] -> {Q2|K2|V2}.
// Output layout is HEAD-MAJOR: Q2/K2 = [b][h][s][4], V2 = [b][h][s][8]
// so the attention kernel reads contiguous per-(b,h) slices (kills the
// 4x/2x cache-line over-fetch seen in R4: FETCH 57 MB -> ~17 MB).
// blockIdx = br*4 + bj; bj selects {Wq, Wk, Wv[:,0:256], Wv[:,256:512]}.
// ---------------------------------------------------------------------------
__global__ __launch_bounds__(256) void proj_kernel(
    const float* __restrict__ xq, const float* __restrict__ xkv,
    const float* __restrict__ Wq, const float* __restrict__ Wk,
    const float* __restrict__ Wv,
    float* __restrict__ Q2, float* __restrict__ K2, float* __restrict__ V2)
{
    __shared__ float xt[KC * MR];   // [k][r]  4 KB
    __shared__ float wt[KC * NC];   // [k][c] 32 KB

    const int t  = threadIdx.x;
    const int bj = blockIdx.x & 3;
    const int br = blockIdx.x >> 2;
    const int r0 = br * MR;

    const float* X; const float* W; int ldw; int c0;
    if (bj == 0)      { X = xq;  W = Wq; ldw = 256; c0 = 0;   }
    else if (bj == 1) { X = xkv; W = Wk; ldw = 256; c0 = 0;   }
    else if (bj == 2) { X = xkv; W = Wv; ldw = 512; c0 = 0;   }
    else              { X = xkv; W = Wv; ldw = 512; c0 = 256; }

    const int rg = t >> 6;          // wave id -> rows rg*8..rg*8+7
    const int cq = t & 63;          // cols cq*4..cq*4+3
    const int rs = t & 31;          // x-staging: row
    const int kq = t >> 5;          // x-staging: k-quad 0..7

    float4 acc[8];
#pragma unroll
    for (int r = 0; r < 8; ++r) acc[r] = make_float4(0.f, 0.f, 0.f, 0.f);

    for (int kc = 0; kc < D_MODEL; kc += KC) {
        // ---- stage x tile (transposed [k][r]; 2-way bank groups = free) ----
        const float4 xa = *(const float4*)(X + (long)(r0 + rs) * D_MODEL + kc + kq * 4);
        xt[(kq * 4 + 0) * MR + rs] = xa.x;
        xt[(kq * 4 + 1) * MR + rs] = xa.y;
        xt[(kq * 4 + 2) * MR + rs] = xa.z;
        xt[(kq * 4 + 3) * MR + rs] = xa.w;

        // ---- stage W tile: wave rg loads rows i*4+rg, 1 KB contiguous ----
#pragma unroll
        for (int i = 0; i < 8; ++i) {
            const int row = i * 4 + rg;
            *(float4*)(wt + row * NC + cq * 4) =
                *(const float4*)(W + (long)(kc + row) * ldw + c0 + cq * 4);
        }
        __syncthreads();

        // ---- compute: 8x4 register block, 32 FMA per k ----
#pragma unroll 4
        for (int k = 0; k < KC; ++k) {
            const float4 w4 = *(const float4*)(wt + k * NC + cq * 4);
            const float4 x0 = *(const float4*)(xt + k * MR + rg * 8);
            const float4 x1 = *(const float4*)(xt + k * MR + rg * 8 + 4);
            const float xr[8] = {x0.x, x0.y, x0.z, x0.w, x1.x, x1.y, x1.z, x1.w};
#pragma unroll
            for (int r = 0; r < 8; ++r) {
                acc[r].x = fmaf(xr[r], w4.x, acc[r].x);
                acc[r].y = fmaf(xr[r], w4.y, acc[r].y);
                acc[r].z = fmaf(xr[r], w4.z, acc[r].z);
                acc[r].w = fmaf(xr[r], w4.w, acc[r].w);
            }
        }
        __syncthreads();
    }

    // ---- epilogue: head-major scatter (L2 merges adjacent s-rows) ----
    const int b = r0 >> 9;              // all 32 rows of a block share b
    const int sb = (r0 & 511) + rg * 8;
    if (bj <= 1) {
        float* dst = (bj == 0) ? Q2 : K2;
#pragma unroll
        for (int r = 0; r < 8; ++r)
            *(float4*)(dst + (((long)b * HEAD + cq) * SEQ + sb + r) * 4) = acc[r];
    } else {
        const int col = c0 + cq * 4;
        const int h = col >> 3;
        const int off = col & 7;        // 0 or 4
#pragma unroll
        for (int r = 0; r < 8; ++r)
            *(float4*)(V2 + (((long)b * HEAD + h) * SEQ + sb + r) * 8 + off) = acc[r];
    }
}

// ---------------------------------------------------------------------------
// Attention: one block per (b, h, q-half); 256 threads, 1 query/thread.
// Head-major inputs -> contiguous staging loads. Online softmax, groups of 8.
// Causal quirk preserved: masked (s>q) scores are exactly 0 and participate;
// their lump = exp(-M) * (count, suffixSumV) via chunk-granular suffix sums.
// ---------------------------------------------------------------------------
__global__ __launch_bounds__(256) void attn_kernel(
    const float* __restrict__ Q2, const float* __restrict__ K2,
    const float* __restrict__ V2, float* __restrict__ O, int causal)
{
    extern __shared__ float smem[];
    float* Kl = smem;                 // SEQ*DK = 2048 floats
    float* Vl = smem + SEQ * DK;      // SEQ*DV = 4096 floats
    float* cs = Vl + SEQ * DV;        // 33*DV  =  264 floats (causal only)

    const int t = threadIdx.x;
    const int bh = blockIdx.x >> 1;   // b*64 + h
    const int qhalf = blockIdx.x & 1;
    const int b = bh >> 6;
    const int h = bh & 63;

    // contiguous slices: K 8 KB, V 16 KB
    const float4* Ks = (const float4*)(K2 + (long)bh * SEQ * DK);
    ((float4*)Kl)[t]       = Ks[t];
    ((float4*)Kl)[t + 256] = Ks[t + 256];
    const float4* Vs = (const float4*)(V2 + (long)bh * SEQ * DV);
#pragma unroll
    for (int i = 0; i < 4; ++i)
        ((float4*)Vl)[t + i * 256] = Vs[t + i * 256];
    __syncthreads();

    if (causal) {
        const int ch = t >> 3, d = t & 7;
        float s16 = 0.f;
#pragma unroll
        for (int i = 0; i < 16; ++i) s16 += Vl[(ch * 16 + i) * 8 + d];
        cs[ch * 8 + d] = s16;
        __syncthreads();
        if (t < 8) {
            cs[256 + t] = 0.f;
            float run = 0.f;
            for (int c2 = 31; c2 >= 0; --c2) {
                run += cs[c2 * 8 + t];
                cs[c2 * 8 + t] = run;
            }
        }
        __syncthreads();
    }

    const int q = qhalf * 256 + t;
    const float4 qv = *(const float4*)(Q2 + ((long)bh * SEQ + q) * 4);
    const float q0 = qv.x * 0.5f, q1 = qv.y * 0.5f;   // fold 1/sqrt(DK)=0.5
    const float q2 = qv.z * 0.5f, q3 = qv.w * 0.5f;

    const int bound = causal ? q : (SEQ - 1);

    float m = -INFINITY, l = 0.f;
    float a0=0.f,a1=0.f,a2=0.f,a3=0.f,a4=0.f,a5=0.f,a6=0.f,a7=0.f;

    int s0 = 0;
    for (; s0 + 8 <= bound + 1; s0 += 8) {
        float sc[8];
#pragma unroll
        for (int i = 0; i < 8; ++i) {
            const float4 k4 = *(const float4*)(Kl + (s0 + i) * 4);
            sc[i] = fmaf(q0, k4.x, fmaf(q1, k4.y, fmaf(q2, k4.z, q3 * k4.w)));
        }
        float gm = fmaxf(fmaxf(fmaxf(sc[0], sc[1]), fmaxf(sc[2], sc[3])),
                         fmaxf(fmaxf(sc[4], sc[5]), fmaxf(sc[6], sc[7])));
        if (gm > m) {
            float scale = __expf(m - gm);
            l *= scale;
            a0*=scale; a1*=scale; a2*=scale; a3*=scale;
            a4*=scale; a5*=scale; a6*=scale; a7*=scale;
            m = gm;
        }
#pragma unroll
        for (int i = 0; i < 8; ++i) {
            float p = __expf(sc[i] - m);
            l += p;
            const float4 v0 = *(const float4*)(Vl + (s0 + i) * 8);
            const float4 v1 = *(const float4*)(Vl + (s0 + i) * 8 + 4);
            a0 = fmaf(p, v0.x, a0); a1 = fmaf(p, v0.y, a1);
            a2 = fmaf(p, v0.z, a2); a3 = fmaf(p, v0.w, a3);
            a4 = fmaf(p, v1.x, a4); a5 = fmaf(p, v1.y, a5);
            a6 = fmaf(p, v1.z, a6); a7 = fmaf(p, v1.w, a7);
        }
    }
    for (int s = s0; s <= bound; ++s) {
        const float4 k4 = *(const float4*)(Kl + s * 4);
        float sc = fmaf(q0, k4.x, fmaf(q1, k4.y, fmaf(q2, k4.z, q3 * k4.w)));
        if (sc > m) {
            float scale = __expf(m - sc);
            l *= scale;
            a0*=scale; a1*=scale; a2*=scale; a3*=scale;
            a4*=scale; a5*=scale; a6*=scale; a7*=scale;
            m = sc;
        }
        float p = __expf(sc - m);
        l += p;
        const float4 v0 = *(const float4*)(Vl + s * 8);
        const float4 v1 = *(const float4*)(Vl + s * 8 + 4);
        a0 = fmaf(p, v0.x, a0); a1 = fmaf(p, v0.y, a1);
        a2 = fmaf(p, v0.z, a2); a3 = fmaf(p, v0.w, a3);
        a4 = fmaf(p, v1.x, a4); a5 = fmaf(p, v1.y, a5);
        a6 = fmaf(p, v1.z, a6); a7 = fmaf(p, v1.w, a7);
    }

    if (causal && q < SEQ - 1) {
        float M = fmaxf(m, 0.f);
        float scale = __expf(m - M);
        float pm = __expf(-M);
        l = l * scale + pm * (float)(SEQ - 1 - q);
        int nq = q + 1;
        int cq2 = nq >> 4;
        float sv[8];
#pragma unroll
        for (int d = 0; d < 8; ++d) sv[d] = cs[(cq2 + 1) * 8 + d];
        for (int s = nq; s < (cq2 + 1) * 16; ++s) {
            const float4 v0 = *(const float4*)(Vl + s * 8);
            const float4 v1 = *(const float4*)(Vl + s * 8 + 4);
            sv[0]+=v0.x; sv[1]+=v0.y; sv[2]+=v0.z; sv[3]+=v0.w;
            sv[4]+=v1.x; sv[5]+=v1.y; sv[6]+=v1.z; sv[7]+=v1.w;
        }
        a0 = a0*scale + pm*sv[0]; a1 = a1*scale + pm*sv[1];
        a2 = a2*scale + pm*sv[2]; a3 = a3*scale + pm*sv[3];
        a4 = a4*scale + pm*sv[4]; a5 = a5*scale + pm*sv[5];
        a6 = a6*scale + pm*sv[6]; a7 = a7*scale + pm*sv[7];
    }

    float inv = 1.0f / l;
    const long obase = (long)b * SEQ * 512 + (long)q * 512 + h * DV;  // row-major
    *(float4*)(O + obase)     = make_float4(a0*inv, a1*inv, a2*inv, a3*inv);
    *(float4*)(O + obase + 4) = make_float4(a4*inv, a5*inv, a6*inv, a7*inv);
}

// ---------------------------------------------------------------------------
// Fused residual + LayerNorm + MLP (512 -> 10 -> 512).
// One WAVE per row (no __syncthreads); 256 threads = 4 rows/block.
// ---------------------------------------------------------------------------
__global__ __launch_bounds__(256) void ln_mlp_kernel(
    const float* __restrict__ x, const float* __restrict__ fx,
    const float* __restrict__ g, const float* __restrict__ beta,
    const float* __restrict__ w1, const float* __restrict__ b1,
    const float* __restrict__ w2, const float* __restrict__ b2,
    float* __restrict__ out)
{
    const int t = threadIdx.x;
    const int lane = t & 63;
    const int row = blockIdx.x * 4 + (t >> 6);
    const long base = (long)row * D_MODEL;
    const int e0 = lane * 8;

    const float4 xa = *(const float4*)(x + base + e0);
    const float4 xb = *(const float4*)(x + base + e0 + 4);
    const float4 fa = *(const float4*)(fx + base + e0);
    const float4 fb = *(const float4*)(fx + base + e0 + 4);
    float z[8] = {xa.x+fa.x, xa.y+fa.y, xa.z+fa.z, xa.w+fa.w,
                  xb.x+fb.x, xb.y+fb.y, xb.z+fb.z, xb.w+fb.w};

    float sum = 0.f;
#pragma unroll
    for (int j = 0; j < 8; ++j) sum += z[j];
#pragma unroll
    for (int o = 32; o > 0; o >>= 1) sum += __shfl_xor(sum, o);
    float mu = sum * (1.0f / 512.0f);

    float d[8], ss = 0.f;
#pragma unroll
    for (int j = 0; j < 8; ++j) { d[j] = z[j] - mu; ss += d[j] * d[j]; }
#pragma unroll
    for (int o = 32; o > 0; o >>= 1) ss += __shfl_xor(ss, o);
    float rs = rsqrtf(ss * (1.0f / 512.0f) + 1e-5f);

    const float4 ga = *(const float4*)(g + e0);
    const float4 gb = *(const float4*)(g + e0 + 4);
    const float4 ba = *(const float4*)(beta + e0);
    const float4 bb = *(const float4*)(beta + e0 + 4);
    const float gg[8] = {ga.x,ga.y,ga.z,ga.w,gb.x,gb.y,gb.z,gb.w};
    const float bt[8] = {ba.x,ba.y,ba.z,ba.w,bb.x,bb.y,bb.z,bb.w};
    float y[8];
#pragma unroll
    for (int j = 0; j < 8; ++j) y[j] = d[j] * rs * gg[j] + bt[j];

    float part[HIDD];
#pragma unroll
    for (int i = 0; i < HIDD; ++i) {
        const float4 wa = *(const float4*)(w1 + i * 512 + e0);
        const float4 wb = *(const float4*)(w1 + i * 512 + e0 + 4);
        part[i] = y[0]*wa.x + y[1]*wa.y + y[2]*wa.z + y[3]*wa.w
                + y[4]*wb.x + y[5]*wb.y + y[6]*wb.z + y[7]*wb.w;
    }
#pragma unroll
    for (int i = 0; i < HIDD; ++i)
#pragma unroll
        for (int o = 32; o > 0; o >>= 1) part[i] += __shfl_xor(part[i], o);

    float hv[HIDD];
#pragma unroll
    for (int i = 0; i < HIDD; ++i) hv[i] = fmaxf(part[i] + b1[i], 0.f);

    float o8[8];
#pragma unroll
    for (int j = 0; j < 8; ++j) o8[j] = b2[e0 + j];
#pragma unroll
    for (int i = 0; i < HIDD; ++i)
#pragma unroll
        for (int j = 0; j < 8; ++j)
            o8[j] = fmaf(hv[i], w2[(long)(e0 + j) * 10 + i], o8[j]);

    *(float4*)(out + base + e0)     = make_float4(o8[0], o8[1], o8[2], o8[3]);
    *(float4*)(out + base + e0 + 4) = make_float4(o8[4], o8[5], o8[6], o8[7]);
}

extern "C" void kernel_launch(void* const* d_in, const int* in_sizes, int n_in,
                              void* d_out, int out_size, void* d_ws, size_t ws_size,
                              hipStream_t stream) {
    (void)in_sizes; (void)n_in; (void)out_size; (void)ws_size;
    const float* x    = (const float*)d_in[0];
    const float* xenc = (const float*)d_in[1];
    const float* Wq   = (const float*)d_in[2];
    const float* Wk   = (const float*)d_in[3];
    const float* Wv   = (const float*)d_in[4];
    const float* ln_g = (const float*)d_in[5];
    const float* ln_b = (const float*)d_in[6];
    const float* w1   = (const float*)d_in[7];
    const float* b1   = (const float*)d_in[8];
    const float* w2   = (const float*)d_in[9];
    const float* b2   = (const float*)d_in[10];
    float* out = (float*)d_out;

    float* ws = (float*)d_ws;
    float* Q2 = ws;                   // 1,048,576 floats [b][h][s][4]
    float* K2 = Q2 + 1048576;         // 1,048,576 floats [b][h][s][4]
    float* V2 = K2 + 1048576;         // 2,097,152 floats [b][h][s][8]
    float* A  = V2 + 2097152;         // 2,097,152 floats row-major [b][s][512]

    const int nrows = BATCH * SEQ;    // 4096
    const size_t lds_cross  = (size_t)(SEQ * DK + SEQ * DV) * 4;          // 24576
    const size_t lds_causal = lds_cross + (size_t)(33 * DV) * 4;          // 25632
    const int proj_grid = (nrows / MR) * 4;                               // 512

    // Stage 1: self-attention (causal multiplicative mask)
    proj_kernel<<<dim3(proj_grid), 256, 0, stream>>>(x, x, Wq, Wk, Wv, Q2, K2, V2);
    attn_kernel<<<dim3(BATCH * HEAD * 2), 256, lds_causal, stream>>>(Q2, K2, V2, A, 1);

    // Stage 2: cross-attention (same weights — faithful quirk)
    proj_kernel<<<dim3(proj_grid), 256, 0, stream>>>(A, xenc, Wq, Wk, Wv, Q2, K2, V2);
    attn_kernel<<<dim3(BATCH * HEAD * 2), 256, lds_cross, stream>>>(Q2, K2, V2, A, 0);

    // Stage 3: residual(x) + LayerNorm + MLP
    ln_mlp_kernel<<<dim3(nrows / 4), 256, 0, stream>>>(x, A, ln_g, ln_b,
                                                       w1, b1, w2, b2, out);
}